// Round 11
// baseline (701.419 us; speedup 1.0000x reference)
//
#include <hip/hip_runtime.h>
#include <math.h>

#define NB 8
#define C 256
#define HW 1024
#define NS 64

typedef unsigned short u16;
typedef __attribute__((ext_vector_type(8))) short bf16x8;
typedef __attribute__((ext_vector_type(4))) float f32x4;

__device__ __forceinline__ u16 f2bf(float x) {
    union { float f; unsigned u; } v; v.f = x;
    unsigned r = v.u + 0x7fffu + ((v.u >> 16) & 1u);
    return (u16)(r >> 16);
}
__device__ __forceinline__ float bf2f(u16 h) {
    union { unsigned u; float f; } v; v.u = ((unsigned)h) << 16; return v.f;
}
__device__ __forceinline__ void splitbf(float x, u16& h, u16& l) {
    h = f2bf(x);
    l = f2bf(x - bf2f(h));
}

__device__ __forceinline__ float blockReduceSum(float v, float* s4) {
    #pragma unroll
    for (int o = 32; o; o >>= 1) v += __shfl_down(v, o);
    __syncthreads();
    if ((threadIdx.x & 63) == 0) s4[threadIdx.x >> 6] = v;
    __syncthreads();
    return s4[0] + s4[1] + s4[2] + s4[3];
}

// ---------------- once-per-launch: concat conv weights/biases ----------------
__global__ void k_prepw(const float* __restrict__ ws1, const float* __restrict__ bs1,
                        const float* __restrict__ ws11, const float* __restrict__ bs11,
                        float* __restrict__ WCAT, float* __restrict__ BCAT) {
    int tid = blockIdx.x * 256 + threadIdx.x;
    if (tid < 64 * C) {
        WCAT[tid] = ws1[tid];
        WCAT[64 * C + tid] = ws11[tid];
    }
    if (tid < 64) { BCAT[tid] = bs1[tid]; BCAT[64 + tid] = bs11[tid]; }
}

// ---------------- generic 64x64-tile transpose: in[R][Cin] -> out[Cin][R] ----------------
template<int R, int CIN>
__global__ void k_transp(const float* __restrict__ in, long long sIn,
                         float* __restrict__ outp, long long sOut) {
    int ti = blockIdx.x, tj = blockIdx.y, n = blockIdx.z, tid = threadIdx.x;
    int i0 = ti * 64, j0 = tj * 64;
    const float* ib = in + (size_t)n * sIn;
    float* ob = outp + (size_t)n * sOut;
    __shared__ float L[64][65];
    for (int idx = tid; idx < 4096; idx += 256) {
        int r = idx >> 6, c = idx & 63;
        L[r][c] = ib[(size_t)(i0 + r) * CIN + (j0 + c)];
    }
    __syncthreads();
    for (int idx = tid; idx < 4096; idx += 256) {
        int r = idx >> 6, c = idx & 63;
        ob[(size_t)(j0 + r) * R + (i0 + c)] = L[c][r];
    }
}

__global__ void k_pooled(const float* __restrict__ seg, float* __restrict__ pooled) {
    int c = blockIdx.x, n = blockIdx.y, tid = threadIdx.x;
    const float* row = seg + ((size_t)n * C + c) * HW;
    float acc = row[tid] + row[tid + 256] + row[tid + 512] + row[tid + 768];
    __shared__ float s4[4];
    float r = blockReduceSum(acc, s4);
    if (tid == 0) pooled[n * C + c] = r * (1.0f / HW);
}

__global__ void k_ca(const float* __restrict__ pooled, const float* __restrict__ wmlp,
                     const float* __restrict__ bmlp, float* __restrict__ ca) {
    int n = blockIdx.x, s = threadIdx.x;
    __shared__ float pl[C];
    for (int i = s; i < C; i += 64) pl[i] = pooled[n * C + i];
    __syncthreads();
    float acc = 0.f;
    for (int c = 0; c < C; ++c) acc += pl[c] * wmlp[s * C + c];
    float r = acc + bmlp[s];
    ca[n * NS + s] = r > 0.f ? r : 0.f;
}

// ---------------- chunked channel maxes ----------------
__global__ void k_maxes(const float* __restrict__ seg, const float* __restrict__ edge,
                        float* __restrict__ smax, float* __restrict__ emax) {
    int pos = blockIdx.x * 256 + threadIdx.x;
    int n = blockIdx.y, ch = blockIdx.z;
    const float* sb = seg + (size_t)n * C * HW + (size_t)(ch * 32) * HW + pos;
    const float* eb = edge + (size_t)n * C * HW + (size_t)(ch * 32) * HW + pos;
    float ms = -3.402823466e38f, me = -3.402823466e38f;
    #pragma unroll 8
    for (int c = 0; c < 32; ++c) {
        float s = sb[(size_t)c * HW];
        ms = fmaxf(ms, s);
        me = fmaxf(me, s * eb[(size_t)c * HW]);
    }
    smax[((size_t)ch * NB + n) * HW + pos] = ms;
    emax[((size_t)ch * NB + n) * HW + pos] = me;
}

__global__ void k_maxfin(const float* __restrict__ smax, const float* __restrict__ emax,
                         const float* __restrict__ ws2, const float* __restrict__ bs2,
                         const float* __restrict__ ws3, const float* __restrict__ bs3,
                         float* __restrict__ segss, float* __restrict__ edgemm) {
    int pos = blockIdx.x * 256 + threadIdx.x;
    int n = blockIdx.y;
    float ms = -3.402823466e38f, me = -3.402823466e38f;
    #pragma unroll
    for (int ch = 0; ch < 8; ++ch) {
        ms = fmaxf(ms, smax[((size_t)ch * NB + n) * HW + pos]);
        me = fmaxf(me, emax[((size_t)ch * NB + n) * HW + pos]);
    }
    segss[n * HW + pos] = ws2[0] * ms + bs2[0];
    edgemm[n * HW + pos] = ws3[0] * me + bs3[0];
}

// ---------------- u, v ----------------
__global__ void k_uv(const float* __restrict__ segsc, const float* __restrict__ ca,
                     float* __restrict__ u, float* __restrict__ vv) {
    int pos = blockIdx.x * 256 + threadIdx.x;
    int n = blockIdx.y, role = blockIdx.z;
    const float* flat = segsc + (size_t)n * 128 * HW;
    __shared__ float cs[NS];
    if (threadIdx.x < NS) cs[threadIdx.x] = ca[n * NS + threadIdx.x];
    __syncthreads();
    if (role == 0) {
        const float* base = flat + (size_t)pos * NS;
        float acc = 0.f;
        #pragma unroll
        for (int s = 0; s < NS; ++s) acc += base[s] * cs[s];
        u[n * HW + pos] = acc;
    } else {
        float acc = 0.f;
        #pragma unroll
        for (int s = 0; s < NS; ++s) acc += cs[s] * flat[(size_t)s * HW + pos];
        vv[n * HW + pos] = acc;
    }
}

// ===================== fused MFMA B-build + threshold + symmetrize + rowsum =====================
__global__ __launch_bounds__(256) void k_bbuild(
    const float* __restrict__ Aflat, long long sA,
    const float* __restrict__ CT,
    const float* __restrict__ em, const float* __restrict__ ss,
    float* __restrict__ B, float* __restrict__ dsum) {
    constexpr int LDK = 72;
    constexpr int TSZ = 64 * LDK;
    __shared__ __align__(16) u16 sm[4 * 2 * TSZ];
    int pi = blockIdx.x, n = blockIdx.y, tid = threadIdx.x;
    int i = 0, base = 0;
    while (pi >= base + (16 - i)) { base += 16 - i; ++i; }
    int j = i + (pi - base);
    int i0 = i * 64, j0 = j * 64;
    bool diag = (i == j);
    const float* An = Aflat + (size_t)n * sA;
    const float* Cn = CT + (size_t)n * NS * HW;
    const float* emn = em + n * HW;
    const float* ssn = ss + n * HW;
    float* Bn = B + (size_t)n * HW * HW;

    auto stage = [&](int t, const float* src, int r0) {
        u16* hi = sm + t * 2 * TSZ;
        u16* lo = hi + TSZ;
        #pragma unroll
        for (int p = 0; p < 2; ++p) {
            int e = (p * 256 + tid) * 8;
            int r = e >> 6, k0 = e & 63;
            const float* s = src + (size_t)(r0 + r) * 64 + k0;
            float4 w0 = *(const float4*)s;
            float4 w1 = *(const float4*)(s + 4);
            float xs[8] = {w0.x, w0.y, w0.z, w0.w, w1.x, w1.y, w1.z, w1.w};
            u16 h[8], l[8];
            #pragma unroll
            for (int q = 0; q < 8; ++q) splitbf(xs[q], h[q], l[q]);
            int b = r * LDK + k0;
            *(bf16x8*)(hi + b) = (bf16x8){(short)h[0], (short)h[1], (short)h[2], (short)h[3],
                                          (short)h[4], (short)h[5], (short)h[6], (short)h[7]};
            *(bf16x8*)(lo + b) = (bf16x8){(short)l[0], (short)l[1], (short)l[2], (short)l[3],
                                          (short)l[4], (short)l[5], (short)l[6], (short)l[7]};
        }
    };
    stage(0, An, i0);
    stage(2, Cn, i0);
    if (!diag) { stage(1, An, j0); stage(3, Cn, j0); }
    __syncthreads();

    int lane = tid & 63, wv = tid >> 6;
    int g = lane >> 4;
    f32x4 acc1[4], acc2[4];
    #pragma unroll
    for (int ni = 0; ni < 4; ++ni) {
        acc1[ni] = (f32x4){0.f, 0.f, 0.f, 0.f};
        acc2[ni] = (f32x4){0.f, 0.f, 0.f, 0.f};
    }

    const u16* AiH = sm + 0 * 2 * TSZ; const u16* AiL = AiH + TSZ;
    const u16* AjH = sm + 1 * 2 * TSZ; const u16* AjL = AjH + TSZ;
    const u16* BiH = sm + 2 * 2 * TSZ; const u16* BiL = BiH + TSZ;
    const u16* BjH = sm + 3 * 2 * TSZ; const u16* BjL = BjH + TSZ;

    #pragma unroll
    for (int kk = 0; kk < 2; ++kk) {
        int kl = kk * 32 + g * 8;
        int arow = wv * 16 + (lane & 15);
        bf16x8 a1h = *(const bf16x8*)(AiH + arow * LDK + kl);
        bf16x8 a1l = *(const bf16x8*)(AiL + arow * LDK + kl);
        bf16x8 a2h, a2l;
        if (!diag) {
            a2h = *(const bf16x8*)(AjH + arow * LDK + kl);
            a2l = *(const bf16x8*)(AjL + arow * LDK + kl);
        }
        #pragma unroll
        for (int ni = 0; ni < 4; ++ni) {
            int brow = ni * 16 + (lane & 15);
            if (diag) {
                bf16x8 bh = *(const bf16x8*)(BiH + brow * LDK + kl);
                bf16x8 bl = *(const bf16x8*)(BiL + brow * LDK + kl);
                acc1[ni] = __builtin_amdgcn_mfma_f32_16x16x32_bf16(a1h, bh, acc1[ni], 0, 0, 0);
                acc1[ni] = __builtin_amdgcn_mfma_f32_16x16x32_bf16(a1h, bl, acc1[ni], 0, 0, 0);
                acc1[ni] = __builtin_amdgcn_mfma_f32_16x16x32_bf16(a1l, bh, acc1[ni], 0, 0, 0);
            } else {
                bf16x8 b1h = *(const bf16x8*)(BjH + brow * LDK + kl);
                bf16x8 b1l = *(const bf16x8*)(BjL + brow * LDK + kl);
                acc1[ni] = __builtin_amdgcn_mfma_f32_16x16x32_bf16(a1h, b1h, acc1[ni], 0, 0, 0);
                acc1[ni] = __builtin_amdgcn_mfma_f32_16x16x32_bf16(a1h, b1l, acc1[ni], 0, 0, 0);
                acc1[ni] = __builtin_amdgcn_mfma_f32_16x16x32_bf16(a1l, b1h, acc1[ni], 0, 0, 0);
                bf16x8 b2h = *(const bf16x8*)(BiH + brow * LDK + kl);
                bf16x8 b2l = *(const bf16x8*)(BiL + brow * LDK + kl);
                acc2[ni] = __builtin_amdgcn_mfma_f32_16x16x32_bf16(a2h, b2h, acc2[ni], 0, 0, 0);
                acc2[ni] = __builtin_amdgcn_mfma_f32_16x16x32_bf16(a2h, b2l, acc2[ni], 0, 0, 0);
                acc2[ni] = __builtin_amdgcn_mfma_f32_16x16x32_bf16(a2l, b2h, acc2[ni], 0, 0, 0);
            }
        }
    }
    __syncthreads();

    float* t1 = (float*)sm;
    float* t2 = t1 + 64 * 65;
    float x[4][4], y[4][4];
    #pragma unroll
    for (int ni = 0; ni < 4; ++ni) {
        int col = ni * 16 + (lane & 15);
        #pragma unroll
        for (int r = 0; r < 4; ++r) {
            int row = wv * 16 + g * 4 + r;
            float v1 = acc1[ni][r] * emn[i0 + row] * ssn[j0 + col];
            v1 = v1 < 0.15f ? 0.f : v1;
            x[ni][r] = v1;
            t1[row * 65 + col] = v1;
            if (!diag) {
                float v2 = acc2[ni][r] * emn[j0 + row] * ssn[i0 + col];
                v2 = v2 < 0.15f ? 0.f : v2;
                y[ni][r] = v2;
                t2[row * 65 + col] = v2;
            }
        }
    }
    __syncthreads();

    float rs1[4] = {0.f, 0.f, 0.f, 0.f}, rs2[4] = {0.f, 0.f, 0.f, 0.f};
    #pragma unroll
    for (int ni = 0; ni < 4; ++ni) {
        int col = ni * 16 + (lane & 15);
        #pragma unroll
        for (int r = 0; r < 4; ++r) {
            int row = wv * 16 + g * 4 + r;
            float s1 = 0.5f * (x[ni][r] + (diag ? t1[col * 65 + row] : t2[col * 65 + row]));
            Bn[(size_t)(i0 + row) * HW + j0 + col] = s1;
            rs1[r] += s1;
            if (!diag) {
                float s2 = 0.5f * (y[ni][r] + t1[col * 65 + row]);
                Bn[(size_t)(j0 + row) * HW + i0 + col] = s2;
                rs2[r] += s2;
            }
        }
    }
    #pragma unroll
    for (int r = 0; r < 4; ++r) {
        #pragma unroll
        for (int m = 1; m < 16; m <<= 1) {
            rs1[r] += __shfl_xor(rs1[r], m);
            rs2[r] += __shfl_xor(rs2[r], m);
        }
    }
    if ((lane & 15) == 0) {
        #pragma unroll
        for (int r = 0; r < 4; ++r) {
            int row = wv * 16 + g * 4 + r;
            atomicAdd(&dsum[n * HW + i0 + row], rs1[r]);
            if (!diag) atomicAdd(&dsum[n * HW + j0 + row], rs2[r]);
        }
    }
}

// ===================== MFMA split-bf16 NT-GEMM (certified), 64x64 tiles =====================
// MODE 0: Ct[col*ldc+row] = acc
// MODE 2: C[row*ldc+col] = relu(acc + e1[row]) + e2[n][row*ldc+col]
// MODE 3: C[row*ldc+col] = 0.5*acc + 0.5*e2[n][row*ldc+col]
// MODE 4: Ct[col*ldc+row] = 0.5*acc + 0.5*e2[n][row*HW+col]
// MODE 5: C[row*ldc+col] = acc + e1[row]
template<int BM, int BN, int MODE>
__global__ __launch_bounds__(256) void k_mfma2(
    const float* __restrict__ Af, long long sA, int lda,
    const float* __restrict__ Bf, long long sB, int ldb,
    int K,
    float* __restrict__ Cf, long long sCf, int ldc,
    const float* __restrict__ e1,
    const float* __restrict__ e2, long long se2) {
    constexpr int WM = BM / 32;
    constexpr int WN = BN / 32;
    constexpr int LDK = 72;
    __shared__ __align__(16) u16 sAH[BM * LDK], sAL[BM * LDK];
    __shared__ __align__(16) u16 sBH[BN * LDK], sBL[BN * LDK];
    int n = blockIdx.z;
    int q0 = blockIdx.x * BN, m0 = blockIdx.y * BM;
    int tid = threadIdx.x, lane = tid & 63, wv = tid >> 6;
    int wm = wv >> 1, wn = wv & 1;

    f32x4 acc[WM][WN];
    #pragma unroll
    for (int mi = 0; mi < WM; ++mi)
        #pragma unroll
        for (int ni = 0; ni < WN; ++ni)
            acc[mi][ni] = (f32x4){0.f, 0.f, 0.f, 0.f};

    for (int kt = 0; kt < K; kt += 64) {
        #pragma unroll
        for (int p = 0; p < BM / 32; ++p) {
            int e = (p * 256 + tid) * 8;
            int r = e >> 6, k0 = e & 63;
            const float* src = Af + (size_t)n * sA + (size_t)(m0 + r) * lda + kt + k0;
            float4 w0 = *(const float4*)src;
            float4 w1 = *(const float4*)(src + 4);
            float xs[8] = {w0.x, w0.y, w0.z, w0.w, w1.x, w1.y, w1.z, w1.w};
            u16 h[8], l[8];
            #pragma unroll
            for (int q = 0; q < 8; ++q) splitbf(xs[q], h[q], l[q]);
            int b = r * LDK + k0;
            *(bf16x8*)(sAH + b) = (bf16x8){(short)h[0], (short)h[1], (short)h[2], (short)h[3],
                                           (short)h[4], (short)h[5], (short)h[6], (short)h[7]};
            *(bf16x8*)(sAL + b) = (bf16x8){(short)l[0], (short)l[1], (short)l[2], (short)l[3],
                                           (short)l[4], (short)l[5], (short)l[6], (short)l[7]};
        }
        #pragma unroll
        for (int p = 0; p < BN / 32; ++p) {
            int e = (p * 256 + tid) * 8;
            int c = e >> 6, k0 = e & 63;
            const float* src = Bf + (size_t)n * sB + (size_t)(q0 + c) * ldb + kt + k0;
            float4 w0 = *(const float4*)src;
            float4 w1 = *(const float4*)(src + 4);
            float xs[8] = {w0.x, w0.y, w0.z, w0.w, w1.x, w1.y, w1.z, w1.w};
            u16 h[8], l[8];
            #pragma unroll
            for (int q = 0; q < 8; ++q) splitbf(xs[q], h[q], l[q]);
            int b = c * LDK + k0;
            *(bf16x8*)(sBH + b) = (bf16x8){(short)h[0], (short)h[1], (short)h[2], (short)h[3],
                                           (short)h[4], (short)h[5], (short)h[6], (short)h[7]};
            *(bf16x8*)(sBL + b) = (bf16x8){(short)l[0], (short)l[1], (short)l[2], (short)l[3],
                                           (short)l[4], (short)l[5], (short)l[6], (short)l[7]};
        }
        __syncthreads();
        #pragma unroll
        for (int kk = 0; kk < 2; ++kk) {
            int klocal = kk * 32 + (lane >> 4) * 8;
            bf16x8 aH[WM], aL[WM], bH[WN], bL[WN];
            #pragma unroll
            for (int mi = 0; mi < WM; ++mi) {
                int row = (wm * WM + mi) * 16 + (lane & 15);
                aH[mi] = *(const bf16x8*)(sAH + row * LDK + klocal);
                aL[mi] = *(const bf16x8*)(sAL + row * LDK + klocal);
            }
            #pragma unroll
            for (int ni = 0; ni < WN; ++ni) {
                int col = (wn * WN + ni) * 16 + (lane & 15);
                bH[ni] = *(const bf16x8*)(sBH + col * LDK + klocal);
                bL[ni] = *(const bf16x8*)(sBL + col * LDK + klocal);
            }
            #pragma unroll
            for (int mi = 0; mi < WM; ++mi)
                #pragma unroll
                for (int ni = 0; ni < WN; ++ni) {
                    acc[mi][ni] = __builtin_amdgcn_mfma_f32_16x16x32_bf16(aH[mi], bH[ni], acc[mi][ni], 0, 0, 0);
                    acc[mi][ni] = __builtin_amdgcn_mfma_f32_16x16x32_bf16(aH[mi], bL[ni], acc[mi][ni], 0, 0, 0);
                    acc[mi][ni] = __builtin_amdgcn_mfma_f32_16x16x32_bf16(aL[mi], bH[ni], acc[mi][ni], 0, 0, 0);
                }
        }
        __syncthreads();
    }

    #pragma unroll
    for (int mi = 0; mi < WM; ++mi) {
        #pragma unroll
        for (int ni = 0; ni < WN; ++ni) {
            int col = q0 + (wn * WN + ni) * 16 + (lane & 15);
            int rowb = m0 + (wm * WM + mi) * 16 + (lane >> 4) * 4;
            #pragma unroll
            for (int r = 0; r < 4; ++r) {
                int row = rowb + r;
                float val = acc[mi][ni][r];
                if (MODE == 0) {
                    Cf[(size_t)n * sCf + (size_t)col * ldc + row] = val;
                } else if (MODE == 2) {
                    val = fmaxf(val + e1[row], 0.f) + e2[(size_t)n * se2 + (size_t)row * ldc + col];
                    Cf[(size_t)n * sCf + (size_t)row * ldc + col] = val;
                } else if (MODE == 3) {
                    val = 0.5f * val + 0.5f * e2[(size_t)n * se2 + (size_t)row * ldc + col];
                    Cf[(size_t)n * sCf + (size_t)row * ldc + col] = val;
                } else if (MODE == 4) {
                    val = 0.5f * val + 0.5f * e2[(size_t)n * se2 + (size_t)row * HW + col];
                    Cf[(size_t)n * sCf + (size_t)col * ldc + row] = val;
                } else {
                    val = val + e1[row];
                    Cf[(size_t)n * sCf + (size_t)row * ldc + col] = val;
                }
            }
        }
    }
}

// ---------------- adjacency/reduction chain ----------------
__global__ void k_dinv(const float* __restrict__ u, const float* __restrict__ vv,
                       const float* __restrict__ dsum,
                       float* __restrict__ dcinv, float* __restrict__ dsinv) {
    int p = blockIdx.x, n = blockIdx.y, tid = threadIdx.x;
    const float* un = u + n * HW;
    const float* vn = vv + n * HW;
    float up = un[p], vp = vn[p];
    float acc_c = 0.f;
    for (int q = tid; q < HW; q += 256) {
        float x = up * vn[q]; x = x < 0.15f ? 0.f : x;
        float y = un[q] * vp; y = y < 0.15f ? 0.f : y;
        acc_c += 0.5f * (x + y);
    }
    __shared__ float s4[4];
    acc_c = blockReduceSum(acc_c, s4);
    if (tid == 0) {
        dcinv[n * HW + p] = 1.0f / sqrtf(acc_c + 1.0f);
        dsinv[n * HW + p] = 1.0f / sqrtf(dsum[n * HW + p] + 1.0f);
    }
}

// read-only: rowsum of sim_pre (recomputed from Bsym + vectors) -> dfinv
__global__ void k_simsum(const float* __restrict__ B, const float* __restrict__ u,
                         const float* __restrict__ vv, const float* __restrict__ dcinv,
                         const float* __restrict__ dsinv, float* __restrict__ dfinv) {
    int p = blockIdx.x, n = blockIdx.y, tid = threadIdx.x;
    const float* Bb = B + (size_t)n * HW * HW + (size_t)p * HW;
    const float* un = u + n * HW;
    const float* vn = vv + n * HW;
    const float* dci = dcinv + n * HW;
    const float* dsi = dsinv + n * HW;
    float up = un[p], vp = vn[p], dcp = dci[p], dsp = dsi[p];
    float acc = 0.f;
    for (int q = tid; q < HW; q += 256) {
        float x = up * vn[q]; x = x < 0.15f ? 0.f : x;
        float y = un[q] * vp; y = y < 0.15f ? 0.f : y;
        float delta = (q == p) ? 1.0f : 0.0f;
        float val = (0.5f * (x + y) + delta) * dcp * dci[q] + (Bb[q] + delta) * dsp * dsi[q];
        acc += val;
    }
    __shared__ float s4[4];
    acc = blockReduceSum(acc, s4);
    if (tid == 0) dfinv[n * HW + p] = 1.0f / sqrtf(acc + 1.0f);
}

// recompute sim_pre from Bsym + vectors, normalize, write sim (in place) + ACCUM
__global__ void k_norm_accum(float* __restrict__ B, const float* __restrict__ u,
                             const float* __restrict__ vv, const float* __restrict__ dcinv,
                             const float* __restrict__ dsinv, const float* __restrict__ dfinv,
                             float* __restrict__ ACC, int first) {
    int p = blockIdx.x, n = blockIdx.y, tid = threadIdx.x;
    float* Bb = B + (size_t)n * HW * HW + (size_t)p * HW;
    float* Ab = ACC + (size_t)n * HW * HW + (size_t)p * HW;
    const float* un = u + n * HW;
    const float* vn = vv + n * HW;
    const float* dci = dcinv + n * HW;
    const float* dsi = dsinv + n * HW;
    const float* df = dfinv + n * HW;
    float up = un[p], vp = vn[p], dcp = dci[p], dsp = dsi[p], dfp = df[p];
    for (int q = tid; q < HW; q += 256) {
        float x = up * vn[q]; x = x < 0.15f ? 0.f : x;
        float y = un[q] * vp; y = y < 0.15f ? 0.f : y;
        float delta = (q == p) ? 1.0f : 0.0f;
        float sim_pre = (0.5f * (x + y) + delta) * dcp * dci[q] + (Bb[q] + delta) * dsp * dsi[q];
        float val = (sim_pre + delta) * dfp * df[q];
        Bb[q] = val;
        Ab[q] = first ? val : (Ab[q] + val);
    }
}

__global__ void k_final_rowsum(const float* __restrict__ ACC, float* __restrict__ dinv) {
    int p = blockIdx.x, n = blockIdx.y, tid = threadIdx.x;
    const float* Ab = ACC + (size_t)n * HW * HW + (size_t)p * HW;
    float acc = 0.f;
    for (int q = tid; q < HW; q += 256) acc += Ab[q];
    __shared__ float s4[4];
    acc = blockReduceSum(acc, s4);
    if (tid == 0) dinv[n * HW + p] = 1.0f / sqrtf(acc * (1.0f / 3.0f) + 1.0f);
}

__global__ void k_final_norm(float* __restrict__ ACC, const float* __restrict__ dinv,
                             float* __restrict__ rowsf, float* __restrict__ diagrow,
                             float* __restrict__ sqrow) {
    int p = blockIdx.x, n = blockIdx.y, tid = threadIdx.x;
    float* Ab = ACC + (size_t)n * HW * HW + (size_t)p * HW;
    const float* di = dinv + n * HW;
    float dp = di[p];
    float accr = 0.f, accsq = 0.f, accd = 0.f;
    for (int q = tid; q < HW; q += 256) {
        float val = (Ab[q] * (1.0f / 3.0f) + ((q == p) ? 1.f : 0.f)) * dp * di[q];
        Ab[q] = val;
        accr += val;
        accsq += val * val;
        if (q == p) accd = val;
    }
    __shared__ float s4[4];
    accr = blockReduceSum(accr, s4);
    accsq = blockReduceSum(accsq, s4);
    accd = blockReduceSum(accd, s4);
    if (tid == 0) {
        rowsf[n * HW + p] = accr;
        sqrow[n * HW + p] = accsq;
        diagrow[n * HW + p] = accd;
    }
}

__global__ void k_scal(const float* __restrict__ diagrow, const float* __restrict__ sqrow,
                       float* __restrict__ scal) {
    int tid = threadIdx.x;
    float a = 0.f, b = 0.f;
    for (int i = tid; i < NB * HW; i += 256) { a += diagrow[i]; b += sqrow[i]; }
    __shared__ float s4[4];
    a = blockReduceSum(a, s4);
    b = blockReduceSum(b, s4);
    if (tid == 0) { scal[0] = a; scal[1] = b; }
}

__global__ void k_reg(const float* __restrict__ rowsf, const float* __restrict__ scal,
                      float* __restrict__ outreg) {
    int n = blockIdx.x, tid = threadIdx.x;
    float acc = 0.f;
    for (int p = tid; p < HW; p += 256) acc += logf(rowsf[n * HW + p]);
    __shared__ float s4[4];
    acc = blockReduceSum(acc, s4);
    if (tid == 0) {
        float f = -0.1f * acc / 1024.0f + 0.1f * sqrtf(scal[1]) / 1048576.0f;
        outreg[n] = 0.1f * scal[0] + f;
    }
}

__global__ void k_appnp_t(const float* __restrict__ ori, const float* __restrict__ wa1,
                          const float* __restrict__ ba1, const float* __restrict__ wa2,
                          const float* __restrict__ ba2, float* __restrict__ T) {
    int p = blockIdx.x, n = blockIdx.y, tid = threadIdx.x;
    const float* x = ori + (size_t)n * C * HW + (size_t)p * C;
    float xv = x[tid];
    __shared__ float s4[4];
    __shared__ float h[3];
    float d0 = blockReduceSum(xv * wa1[0 * C + tid], s4);
    float d1 = blockReduceSum(xv * wa1[1 * C + tid], s4);
    float d2 = blockReduceSum(xv * wa1[2 * C + tid], s4);
    if (tid == 0) {
        h[0] = fmaxf(d0 + ba1[0], 0.f);
        h[1] = fmaxf(d1 + ba1[1], 0.f);
        h[2] = fmaxf(d2 + ba1[2], 0.f);
    }
    __syncthreads();
    float t = h[0] * wa2[tid * 3 + 0] + h[1] * wa2[tid * 3 + 1] + h[2] * wa2[tid * 3 + 2] + ba2[tid];
    T[(size_t)n * HW * C + (size_t)p * C + tid] = fmaxf(t, 0.f);
}

// =====================================================================================
extern "C" void kernel_launch(void* const* d_in, const int* in_sizes, int n_in,
                              void* d_out, int out_size, void* d_ws, size_t ws_size,
                              hipStream_t stream) {
    const float* seg_in = (const float*)d_in[0];
    const float* edge   = (const float*)d_in[1];
    const float* ws1    = (const float*)d_in[2];
    const float* bs1    = (const float*)d_in[3];
    const float* ws11   = (const float*)d_in[4];
    const float* bs11   = (const float*)d_in[5];
    const float* ws2    = (const float*)d_in[6];
    const float* bs2    = (const float*)d_in[7];
    const float* ws3    = (const float*)d_in[8];
    const float* bs3    = (const float*)d_in[9];
    const float* wmlp   = (const float*)d_in[10];
    const float* bmlp   = (const float*)d_in[11];
    const float* wgcn   = (const float*)d_in[12];
    const float* bgcn   = (const float*)d_in[13];
    const float* wa1    = (const float*)d_in[14];
    const float* ba1    = (const float*)d_in[15];
    const float* wa2    = (const float*)d_in[16];
    const float* ba2    = (const float*)d_in[17];

    float* out = (float*)d_out;
    float* w = (float*)d_ws;
    float* SEG_A   = w; w += (size_t)NB * C * HW;
    float* SEG_SIMT= w; w += (size_t)NB * C * HW;
    float* SEGSC   = w; w += (size_t)NB * 128 * HW;
    float* SEGCT   = w; w += (size_t)NB * NS * HW;
    float* SEGT    = w; w += (size_t)NB * HW * C;
    float* TBUF    = w; w += (size_t)NB * HW * C;
    float* OBUF    = w; w += (size_t)NB * HW * C;
    float* BBUF    = w; w += (size_t)NB * HW * HW;
    float* ACCUM   = w; w += (size_t)NB * HW * HW;
    float* MAXS    = w; w += (size_t)8 * NB * HW;
    float* MAXE    = w; w += (size_t)8 * NB * HW;
    float* WCAT    = w; w += (size_t)128 * C;
    float* BCAT    = w; w += 128;
    float* ubuf    = w; w += NB * HW;
    float* vbuf    = w; w += NB * HW;
    float* ssbuf   = w; w += NB * HW;
    float* embuf   = w; w += NB * HW;
    float* dsum    = w; w += NB * HW;
    float* dcinv   = w; w += NB * HW;
    float* dsinv   = w; w += NB * HW;
    float* dfinv   = w; w += NB * HW;
    float* rowsf   = w; w += NB * HW;
    float* diagrow = w; w += NB * HW;
    float* sqrow   = w; w += NB * HW;
    float* pooled  = w; w += NB * C;
    float* cabuf   = w; w += NB * NS;
    float* scal    = w; w += 16;

    const long long sAdj = (long long)HW * HW;
    const long long sSeg = (long long)C * HW;
    const long long sSC  = (long long)128 * HW;

    k_prepw<<<dim3(64), 256, 0, stream>>>(ws1, bs1, ws11, bs11, WCAT, BCAT);

    for (int it = 0; it < 3; ++it) {
        const float* seg_src = (it == 0) ? seg_in : SEG_A;
        k_transp<C, HW><<<dim3(4, 16, NB), 256, 0, stream>>>(seg_src, sSeg, SEGT, sSeg);
        // both 1x1 convs: SEGSC rows 0-63 seg_s, 64-127 seg_c  (64x64 tiles, 256 blocks)
        k_mfma2<64, 64, 5><<<dim3(16, 2, NB), 256, 0, stream>>>(
            WCAT, 0, C, SEGT, sSeg, C, C,
            SEGSC, sSC, HW, BCAT, nullptr, 0);
        k_transp<NS, HW><<<dim3(1, 16, NB), 256, 0, stream>>>(SEGSC + (size_t)64 * HW, sSC, SEGCT, (long long)NS * HW);
        k_pooled<<<dim3(C, NB), 256, 0, stream>>>(seg_src, pooled);
        k_ca<<<dim3(NB), 64, 0, stream>>>(pooled, wmlp, bmlp, cabuf);
        k_maxes<<<dim3(4, NB, 8), 256, 0, stream>>>(seg_src, edge, MAXS, MAXE);
        k_maxfin<<<dim3(4, NB), 256, 0, stream>>>(MAXS, MAXE, ws2, bs2, ws3, bs3, ssbuf, embuf);
        k_uv<<<dim3(4, NB, 2), 256, 0, stream>>>(SEGSC, cabuf, ubuf, vbuf);
        hipMemsetAsync(dsum, 0, (size_t)NB * HW * sizeof(float), stream);
        k_bbuild<<<dim3(136, NB), 256, 0, stream>>>(SEGSC + (size_t)64 * HW, sSC, SEGCT,
                                                    embuf, ssbuf, BBUF, dsum);
        k_dinv<<<dim3(HW, NB), 256, 0, stream>>>(ubuf, vbuf, dsum, dcinv, dsinv);
        k_simsum<<<dim3(HW, NB), 256, 0, stream>>>(BBUF, ubuf, vbuf, dcinv, dsinv, dfinv);
        k_norm_accum<<<dim3(HW, NB), 256, 0, stream>>>(BBUF, ubuf, vbuf, dcinv, dsinv, dfinv,
                                                       ACCUM, it == 0 ? 1 : 0);
        // seg_sim^T = (seg @ sim)^T : NT, Bsrc = sim (symmetric), MODE 0 -> [pos][ch]
        k_mfma2<64, 64, 0><<<dim3(16, 4, NB), 256, 0, stream>>>(
            seg_src, sSeg, HW, BBUF, sAdj, HW, HW,
            SEG_SIMT, sSeg, C, nullptr, nullptr, 0);
        // seg' = relu(wgcn @ seg_sim + bgcn) + seg : NT, Bsrc = SEG_SIMT, MODE 2
        k_mfma2<64, 64, 2><<<dim3(16, 4, NB), 256, 0, stream>>>(
            wgcn, 0, C, SEG_SIMT, sSeg, C, C,
            SEG_A, sSeg, HW, bgcn, seg_src, sSeg);
    }

    // final adjacency + regularizer
    k_final_rowsum<<<dim3(HW, NB), 256, 0, stream>>>(ACCUM, dcinv);
    k_final_norm<<<dim3(HW, NB), 256, 0, stream>>>(ACCUM, dcinv, rowsf, diagrow, sqrow);
    k_scal<<<dim3(1), 256, 0, stream>>>(diagrow, sqrow, scal);
    k_reg<<<dim3(NB), 256, 0, stream>>>(rowsf, scal, out + (size_t)NB * C * HW);

    // APPNP, transposed: Yt = 0.5 * Xt @ adj + 0.5 * Tt  (adj symmetric)
    k_appnp_t<<<dim3(HW, NB), 256, 0, stream>>>(seg_in, wa1, ba1, wa2, ba2, TBUF);
    k_transp<HW, C><<<dim3(16, 4, NB), 256, 0, stream>>>(TBUF, sSeg, SEG_SIMT, sSeg);  // Tt
    k_mfma2<64, 64, 3><<<dim3(16, 4, NB), 256, 0, stream>>>(
        SEG_SIMT, sSeg, HW, ACCUM, sAdj, HW, HW,
        TBUF, sSeg, HW, nullptr, SEG_SIMT, sSeg);
    k_mfma2<64, 64, 3><<<dim3(16, 4, NB), 256, 0, stream>>>(
        TBUF, sSeg, HW, ACCUM, sAdj, HW, HW,
        OBUF, sSeg, HW, nullptr, SEG_SIMT, sSeg);
    k_mfma2<64, 64, 4><<<dim3(16, 4, NB), 256, 0, stream>>>(
        OBUF, sSeg, HW, ACCUM, sAdj, HW, HW,
        out, sSeg, C, nullptr, SEG_SIMT, sSeg);
}

// Round 12
// 583.943 us; speedup vs baseline: 1.2012x; 1.2012x over previous
//
#include <hip/hip_runtime.h>
#include <math.h>

#define NB 8
#define C 256
#define HW 1024
#define NS 64

typedef unsigned short u16;
typedef __attribute__((ext_vector_type(8))) short bf16x8;
typedef __attribute__((ext_vector_type(4))) float f32x4;

__device__ __forceinline__ u16 f2bf(float x) {
    union { float f; unsigned u; } v; v.f = x;
    unsigned r = v.u + 0x7fffu + ((v.u >> 16) & 1u);
    return (u16)(r >> 16);
}
__device__ __forceinline__ float bf2f(u16 h) {
    union { unsigned u; float f; } v; v.u = ((unsigned)h) << 16; return v.f;
}
__device__ __forceinline__ void splitbf(float x, u16& h, u16& l) {
    h = f2bf(x);
    l = f2bf(x - bf2f(h));
}

__device__ __forceinline__ float blockReduceSum(float v, float* s4) {
    #pragma unroll
    for (int o = 32; o; o >>= 1) v += __shfl_down(v, o);
    __syncthreads();
    if ((threadIdx.x & 63) == 0) s4[threadIdx.x >> 6] = v;
    __syncthreads();
    return s4[0] + s4[1] + s4[2] + s4[3];
}

// ---------------- one-time: split an f32 array into bf16 hi/lo ----------------
__global__ void k_presplit(const float* __restrict__ in, u16* __restrict__ oh,
                           u16* __restrict__ ol, int nElem) {
    for (int i = blockIdx.x * 256 + threadIdx.x; i < nElem; i += gridDim.x * 256) {
        u16 h, l; splitbf(in[i], h, l);
        oh[i] = h; ol[i] = l;
    }
}

// ---------------- one-time: concat + split conv weights ----------------
__global__ void k_prepw(const float* __restrict__ ws1, const float* __restrict__ bs1,
                        const float* __restrict__ ws11, const float* __restrict__ bs11,
                        u16* __restrict__ WCH, u16* __restrict__ WCL, float* __restrict__ BCAT) {
    int tid = blockIdx.x * 256 + threadIdx.x;
    if (tid < 64 * C) {
        u16 h, l;
        splitbf(ws1[tid], h, l);  WCH[tid] = h;          WCL[tid] = l;
        splitbf(ws11[tid], h, l); WCH[64 * C + tid] = h; WCL[64 * C + tid] = l;
    }
    if (tid < 64) { BCAT[tid] = bs1[tid]; BCAT[64 + tid] = bs11[tid]; }
}

// ---------------- transpose f32 [R][CIN] -> split u16 [CIN][R] (+ optional f32) ----------------
template<int R, int CIN, bool WF32>
__global__ void k_transp_split(const float* __restrict__ in, long long sIn,
                               u16* __restrict__ oh, u16* __restrict__ ol,
                               float* __restrict__ of, long long sOut) {
    int ti = blockIdx.x, tj = blockIdx.y, n = blockIdx.z, tid = threadIdx.x;
    int i0 = ti * 64, j0 = tj * 64;
    const float* ib = in + (size_t)n * sIn;
    __shared__ float L[64][65];
    for (int idx = tid; idx < 4096; idx += 256) {
        int r = idx >> 6, c = idx & 63;
        L[r][c] = ib[(size_t)(i0 + r) * CIN + (j0 + c)];
    }
    __syncthreads();
    for (int idx = tid; idx < 4096; idx += 256) {
        int r = idx >> 6, c = idx & 63;
        size_t o = (size_t)n * sOut + (size_t)(j0 + r) * R + (i0 + c);
        float val = L[c][r];
        u16 h, l; splitbf(val, h, l);
        oh[o] = h; ol[o] = l;
        if (WF32) of[o] = val;
    }
}

__global__ void k_pooled(const float* __restrict__ seg, float* __restrict__ pooled) {
    int c = blockIdx.x, n = blockIdx.y, tid = threadIdx.x;
    const float* row = seg + ((size_t)n * C + c) * HW;
    float acc = row[tid] + row[tid + 256] + row[tid + 512] + row[tid + 768];
    __shared__ float s4[4];
    float r = blockReduceSum(acc, s4);
    if (tid == 0) pooled[n * C + c] = r * (1.0f / HW);
}

__global__ void k_ca(const float* __restrict__ pooled, const float* __restrict__ wmlp,
                     const float* __restrict__ bmlp, float* __restrict__ ca) {
    int n = blockIdx.x, s = threadIdx.x;
    __shared__ float pl[C];
    for (int i = s; i < C; i += 64) pl[i] = pooled[n * C + i];
    __syncthreads();
    float acc = 0.f;
    for (int c = 0; c < C; ++c) acc += pl[c] * wmlp[s * C + c];
    float r = acc + bmlp[s];
    ca[n * NS + s] = r > 0.f ? r : 0.f;
}

__global__ void k_maxes(const float* __restrict__ seg, const float* __restrict__ edge,
                        float* __restrict__ smax, float* __restrict__ emax) {
    int pos = blockIdx.x * 256 + threadIdx.x;
    int n = blockIdx.y, ch = blockIdx.z;
    const float* sb = seg + (size_t)n * C * HW + (size_t)(ch * 32) * HW + pos;
    const float* eb = edge + (size_t)n * C * HW + (size_t)(ch * 32) * HW + pos;
    float ms = -3.402823466e38f, me = -3.402823466e38f;
    #pragma unroll 8
    for (int c = 0; c < 32; ++c) {
        float s = sb[(size_t)c * HW];
        ms = fmaxf(ms, s);
        me = fmaxf(me, s * eb[(size_t)c * HW]);
    }
    smax[((size_t)ch * NB + n) * HW + pos] = ms;
    emax[((size_t)ch * NB + n) * HW + pos] = me;
}

__global__ void k_maxfin(const float* __restrict__ smax, const float* __restrict__ emax,
                         const float* __restrict__ ws2, const float* __restrict__ bs2,
                         const float* __restrict__ ws3, const float* __restrict__ bs3,
                         float* __restrict__ segss, float* __restrict__ edgemm) {
    int pos = blockIdx.x * 256 + threadIdx.x;
    int n = blockIdx.y;
    float ms = -3.402823466e38f, me = -3.402823466e38f;
    #pragma unroll
    for (int ch = 0; ch < 8; ++ch) {
        ms = fmaxf(ms, smax[((size_t)ch * NB + n) * HW + pos]);
        me = fmaxf(me, emax[((size_t)ch * NB + n) * HW + pos]);
    }
    segss[n * HW + pos] = ws2[0] * ms + bs2[0];
    edgemm[n * HW + pos] = ws3[0] * me + bs3[0];
}

__global__ void k_uv(const float* __restrict__ segsc, const float* __restrict__ ca,
                     float* __restrict__ u, float* __restrict__ vv) {
    int pos = blockIdx.x * 256 + threadIdx.x;
    int n = blockIdx.y, role = blockIdx.z;
    const float* flat = segsc + (size_t)n * 128 * HW;
    __shared__ float cs[NS];
    if (threadIdx.x < NS) cs[threadIdx.x] = ca[n * NS + threadIdx.x];
    __syncthreads();
    if (role == 0) {
        const float* base = flat + (size_t)pos * NS;
        float acc = 0.f;
        #pragma unroll
        for (int s = 0; s < NS; ++s) acc += base[s] * cs[s];
        u[n * HW + pos] = acc;
    } else {
        float acc = 0.f;
        #pragma unroll
        for (int s = 0; s < NS; ++s) acc += cs[s] * flat[(size_t)s * HW + pos];
        vv[n * HW + pos] = acc;
    }
}

// ===================== fused MFMA B-build (pre-split inputs) =====================
__global__ __launch_bounds__(256) void k_bbuild(
    const u16* __restrict__ AH, const u16* __restrict__ AL, long long sA,
    const u16* __restrict__ CTH, const u16* __restrict__ CTL, long long sCT,
    const float* __restrict__ em, const float* __restrict__ ss,
    float* __restrict__ B, float* __restrict__ dsum) {
    constexpr int LDK = 72;
    constexpr int TSZ = 64 * LDK;
    __shared__ __align__(16) u16 sm[4 * 2 * TSZ];
    int pi = blockIdx.x, n = blockIdx.y, tid = threadIdx.x;
    int i = 0, base = 0;
    while (pi >= base + (16 - i)) { base += 16 - i; ++i; }
    int j = i + (pi - base);
    int i0 = i * 64, j0 = j * 64;
    bool diag = (i == j);
    const u16* AnH = AH + (size_t)n * sA;
    const u16* AnL = AL + (size_t)n * sA;
    const u16* CnH = CTH + (size_t)n * sCT;
    const u16* CnL = CTL + (size_t)n * sCT;
    const float* emn = em + n * HW;
    const float* ssn = ss + n * HW;
    float* Bn = B + (size_t)n * HW * HW;

    auto stage = [&](int t, const u16* srcH, const u16* srcL, int r0) {
        u16* hi = sm + t * 2 * TSZ;
        u16* lo = hi + TSZ;
        #pragma unroll
        for (int p = 0; p < 2; ++p) {
            int e = (p * 256 + tid) * 8;
            int r = e >> 6, k0 = e & 63;
            size_t off = (size_t)(r0 + r) * 64 + k0;
            int b = r * LDK + k0;
            *(bf16x8*)(hi + b) = *(const bf16x8*)(srcH + off);
            *(bf16x8*)(lo + b) = *(const bf16x8*)(srcL + off);
        }
    };
    stage(0, AnH, AnL, i0);
    stage(2, CnH, CnL, i0);
    if (!diag) { stage(1, AnH, AnL, j0); stage(3, CnH, CnL, j0); }
    __syncthreads();

    int lane = tid & 63, wv = tid >> 6;
    int g = lane >> 4;
    f32x4 acc1[4], acc2[4];
    #pragma unroll
    for (int ni = 0; ni < 4; ++ni) {
        acc1[ni] = (f32x4){0.f, 0.f, 0.f, 0.f};
        acc2[ni] = (f32x4){0.f, 0.f, 0.f, 0.f};
    }

    const u16* AiH = sm + 0 * 2 * TSZ; const u16* AiL = AiH + TSZ;
    const u16* AjH = sm + 1 * 2 * TSZ; const u16* AjL = AjH + TSZ;
    const u16* BiH = sm + 2 * 2 * TSZ; const u16* BiL = BiH + TSZ;
    const u16* BjH = sm + 3 * 2 * TSZ; const u16* BjL = BjH + TSZ;

    #pragma unroll
    for (int kk = 0; kk < 2; ++kk) {
        int kl = kk * 32 + g * 8;
        int arow = wv * 16 + (lane & 15);
        bf16x8 a1h = *(const bf16x8*)(AiH + arow * LDK + kl);
        bf16x8 a1l = *(const bf16x8*)(AiL + arow * LDK + kl);
        bf16x8 a2h, a2l;
        if (!diag) {
            a2h = *(const bf16x8*)(AjH + arow * LDK + kl);
            a2l = *(const bf16x8*)(AjL + arow * LDK + kl);
        }
        #pragma unroll
        for (int ni = 0; ni < 4; ++ni) {
            int brow = ni * 16 + (lane & 15);
            if (diag) {
                bf16x8 bh = *(const bf16x8*)(BiH + brow * LDK + kl);
                bf16x8 bl = *(const bf16x8*)(BiL + brow * LDK + kl);
                acc1[ni] = __builtin_amdgcn_mfma_f32_16x16x32_bf16(a1h, bh, acc1[ni], 0, 0, 0);
                acc1[ni] = __builtin_amdgcn_mfma_f32_16x16x32_bf16(a1h, bl, acc1[ni], 0, 0, 0);
                acc1[ni] = __builtin_amdgcn_mfma_f32_16x16x32_bf16(a1l, bh, acc1[ni], 0, 0, 0);
            } else {
                bf16x8 b1h = *(const bf16x8*)(BjH + brow * LDK + kl);
                bf16x8 b1l = *(const bf16x8*)(BjL + brow * LDK + kl);
                acc1[ni] = __builtin_amdgcn_mfma_f32_16x16x32_bf16(a1h, b1h, acc1[ni], 0, 0, 0);
                acc1[ni] = __builtin_amdgcn_mfma_f32_16x16x32_bf16(a1h, b1l, acc1[ni], 0, 0, 0);
                acc1[ni] = __builtin_amdgcn_mfma_f32_16x16x32_bf16(a1l, b1h, acc1[ni], 0, 0, 0);
                bf16x8 b2h = *(const bf16x8*)(BiH + brow * LDK + kl);
                bf16x8 b2l = *(const bf16x8*)(BiL + brow * LDK + kl);
                acc2[ni] = __builtin_amdgcn_mfma_f32_16x16x32_bf16(a2h, b2h, acc2[ni], 0, 0, 0);
                acc2[ni] = __builtin_amdgcn_mfma_f32_16x16x32_bf16(a2h, b2l, acc2[ni], 0, 0, 0);
                acc2[ni] = __builtin_amdgcn_mfma_f32_16x16x32_bf16(a2l, b2h, acc2[ni], 0, 0, 0);
            }
        }
    }
    __syncthreads();

    float* t1 = (float*)sm;
    float* t2 = t1 + 64 * 65;
    float x[4][4], y[4][4];
    #pragma unroll
    for (int ni = 0; ni < 4; ++ni) {
        int col = ni * 16 + (lane & 15);
        #pragma unroll
        for (int r = 0; r < 4; ++r) {
            int row = wv * 16 + g * 4 + r;
            float v1 = acc1[ni][r] * emn[i0 + row] * ssn[j0 + col];
            v1 = v1 < 0.15f ? 0.f : v1;
            x[ni][r] = v1;
            t1[row * 65 + col] = v1;
            if (!diag) {
                float v2 = acc2[ni][r] * emn[j0 + row] * ssn[i0 + col];
                v2 = v2 < 0.15f ? 0.f : v2;
                y[ni][r] = v2;
                t2[row * 65 + col] = v2;
            }
        }
    }
    __syncthreads();

    float rs1[4] = {0.f, 0.f, 0.f, 0.f}, rs2[4] = {0.f, 0.f, 0.f, 0.f};
    #pragma unroll
    for (int ni = 0; ni < 4; ++ni) {
        int col = ni * 16 + (lane & 15);
        #pragma unroll
        for (int r = 0; r < 4; ++r) {
            int row = wv * 16 + g * 4 + r;
            float s1 = 0.5f * (x[ni][r] + (diag ? t1[col * 65 + row] : t2[col * 65 + row]));
            Bn[(size_t)(i0 + row) * HW + j0 + col] = s1;
            rs1[r] += s1;
            if (!diag) {
                float s2 = 0.5f * (y[ni][r] + t1[col * 65 + row]);
                Bn[(size_t)(j0 + row) * HW + i0 + col] = s2;
                rs2[r] += s2;
            }
        }
    }
    #pragma unroll
    for (int r = 0; r < 4; ++r) {
        #pragma unroll
        for (int m = 1; m < 16; m <<= 1) {
            rs1[r] += __shfl_xor(rs1[r], m);
            rs2[r] += __shfl_xor(rs2[r], m);
        }
    }
    if ((lane & 15) == 0) {
        #pragma unroll
        for (int r = 0; r < 4; ++r) {
            int row = wv * 16 + g * 4 + r;
            atomicAdd(&dsum[n * HW + i0 + row], rs1[r]);
            if (!diag) atomicAdd(&dsum[n * HW + j0 + row], rs2[r]);
        }
    }
}

// ===================== MFMA NT-GEMM, pre-split operands (certified math) =====================
// MODE 0: CH/CL[col*ldc+row] = split(acc)                         (u16, transposed store)
// MODE 2: v = relu(acc+e1[row]) + e2[n][row*ldc+col]; Cf + CH/CL at [row*ldc+col]
// MODE 3: v = 0.5*acc + 0.5*e2[n][row*ldc+col]; CH/CL at [row*ldc+col]  (u16 only)
// MODE 4: v = 0.5*acc + 0.5*e2[n][row*HW+col]; Cf[col*ldc+row]    (f32, transposed store)
// MODE 5: v = acc + e1[row]; Cf + CH/CL at [row*ldc+col]
template<int BM, int BN, int MODE>
__global__ __launch_bounds__(256) void k_mfma3(
    const u16* __restrict__ AH, const u16* __restrict__ AL, long long sA, int lda,
    const u16* __restrict__ BH, const u16* __restrict__ BL, long long sB, int ldb,
    int K,
    float* __restrict__ Cf, u16* __restrict__ CH, u16* __restrict__ CL,
    long long sC, int ldc,
    const float* __restrict__ e1,
    const float* __restrict__ e2, long long se2) {
    constexpr int WM = BM / 32;
    constexpr int WN = BN / 32;
    constexpr int LDK = 72;
    __shared__ __align__(16) u16 sAH[BM * LDK], sAL[BM * LDK];
    __shared__ __align__(16) u16 sBH[BN * LDK], sBL[BN * LDK];
    int n = blockIdx.z;
    int q0 = blockIdx.x * BN, m0 = blockIdx.y * BM;
    int tid = threadIdx.x, lane = tid & 63, wv = tid >> 6;
    int wm = wv >> 1, wn = wv & 1;

    f32x4 acc[WM][WN];
    #pragma unroll
    for (int mi = 0; mi < WM; ++mi)
        #pragma unroll
        for (int ni = 0; ni < WN; ++ni)
            acc[mi][ni] = (f32x4){0.f, 0.f, 0.f, 0.f};

    for (int kt = 0; kt < K; kt += 64) {
        #pragma unroll
        for (int p = 0; p < BM / 32; ++p) {
            int e = (p * 256 + tid) * 8;
            int r = e >> 6, k0 = e & 63;
            size_t off = (size_t)n * sA + (size_t)(m0 + r) * lda + kt + k0;
            int b = r * LDK + k0;
            *(bf16x8*)(sAH + b) = *(const bf16x8*)(AH + off);
            *(bf16x8*)(sAL + b) = *(const bf16x8*)(AL + off);
        }
        #pragma unroll
        for (int p = 0; p < BN / 32; ++p) {
            int e = (p * 256 + tid) * 8;
            int c = e >> 6, k0 = e & 63;
            size_t off = (size_t)n * sB + (size_t)(q0 + c) * ldb + kt + k0;
            int b = c * LDK + k0;
            *(bf16x8*)(sBH + b) = *(const bf16x8*)(BH + off);
            *(bf16x8*)(sBL + b) = *(const bf16x8*)(BL + off);
        }
        __syncthreads();
        #pragma unroll
        for (int kk = 0; kk < 2; ++kk) {
            int klocal = kk * 32 + (lane >> 4) * 8;
            bf16x8 aH[WM], aL[WM], bH[WN], bL[WN];
            #pragma unroll
            for (int mi = 0; mi < WM; ++mi) {
                int row = (wm * WM + mi) * 16 + (lane & 15);
                aH[mi] = *(const bf16x8*)(sAH + row * LDK + klocal);
                aL[mi] = *(const bf16x8*)(sAL + row * LDK + klocal);
            }
            #pragma unroll
            for (int ni = 0; ni < WN; ++ni) {
                int col = (wn * WN + ni) * 16 + (lane & 15);
                bH[ni] = *(const bf16x8*)(sBH + col * LDK + klocal);
                bL[ni] = *(const bf16x8*)(sBL + col * LDK + klocal);
            }
            #pragma unroll
            for (int mi = 0; mi < WM; ++mi)
                #pragma unroll
                for (int ni = 0; ni < WN; ++ni) {
                    acc[mi][ni] = __builtin_amdgcn_mfma_f32_16x16x32_bf16(aH[mi], bH[ni], acc[mi][ni], 0, 0, 0);
                    acc[mi][ni] = __builtin_amdgcn_mfma_f32_16x16x32_bf16(aH[mi], bL[ni], acc[mi][ni], 0, 0, 0);
                    acc[mi][ni] = __builtin_amdgcn_mfma_f32_16x16x32_bf16(aL[mi], bH[ni], acc[mi][ni], 0, 0, 0);
                }
        }
        __syncthreads();
    }

    #pragma unroll
    for (int mi = 0; mi < WM; ++mi) {
        #pragma unroll
        for (int ni = 0; ni < WN; ++ni) {
            int col = q0 + (wn * WN + ni) * 16 + (lane & 15);
            int rowb = m0 + (wm * WM + mi) * 16 + (lane >> 4) * 4;
            #pragma unroll
            for (int r = 0; r < 4; ++r) {
                int row = rowb + r;
                float val = acc[mi][ni][r];
                if (MODE == 0) {
                    u16 h, l; splitbf(val, h, l);
                    size_t o = (size_t)n * sC + (size_t)col * ldc + row;
                    CH[o] = h; CL[o] = l;
                } else if (MODE == 2) {
                    val = fmaxf(val + e1[row], 0.f) + e2[(size_t)n * se2 + (size_t)row * ldc + col];
                    size_t o = (size_t)n * sC + (size_t)row * ldc + col;
                    Cf[o] = val;
                    u16 h, l; splitbf(val, h, l);
                    CH[o] = h; CL[o] = l;
                } else if (MODE == 3) {
                    val = 0.5f * val + 0.5f * e2[(size_t)n * se2 + (size_t)row * ldc + col];
                    size_t o = (size_t)n * sC + (size_t)row * ldc + col;
                    u16 h, l; splitbf(val, h, l);
                    CH[o] = h; CL[o] = l;
                } else if (MODE == 4) {
                    val = 0.5f * val + 0.5f * e2[(size_t)n * se2 + (size_t)row * HW + col];
                    Cf[(size_t)n * sC + (size_t)col * ldc + row] = val;
                } else {  // MODE 5
                    val = val + e1[row];
                    size_t o = (size_t)n * sC + (size_t)row * ldc + col;
                    Cf[o] = val;
                    u16 h, l; splitbf(val, h, l);
                    CH[o] = h; CL[o] = l;
                }
            }
        }
    }
}

// ---------------- adjacency/reduction chain ----------------
__global__ void k_dinv(const float* __restrict__ u, const float* __restrict__ vv,
                       const float* __restrict__ dsum,
                       float* __restrict__ dcinv, float* __restrict__ dsinv) {
    int p = blockIdx.x, n = blockIdx.y, tid = threadIdx.x;
    const float* un = u + n * HW;
    const float* vn = vv + n * HW;
    float up = un[p], vp = vn[p];
    float acc_c = 0.f;
    for (int q = tid; q < HW; q += 256) {
        float x = up * vn[q]; x = x < 0.15f ? 0.f : x;
        float y = un[q] * vp; y = y < 0.15f ? 0.f : y;
        acc_c += 0.5f * (x + y);
    }
    __shared__ float s4[4];
    acc_c = blockReduceSum(acc_c, s4);
    if (tid == 0) {
        dcinv[n * HW + p] = 1.0f / sqrtf(acc_c + 1.0f);
        dsinv[n * HW + p] = 1.0f / sqrtf(dsum[n * HW + p] + 1.0f);
    }
}

__global__ void k_simsum(const float* __restrict__ B, const float* __restrict__ u,
                         const float* __restrict__ vv, const float* __restrict__ dcinv,
                         const float* __restrict__ dsinv, float* __restrict__ dfinv) {
    int p = blockIdx.x, n = blockIdx.y, tid = threadIdx.x;
    const float* Bb = B + (size_t)n * HW * HW + (size_t)p * HW;
    const float* un = u + n * HW;
    const float* vn = vv + n * HW;
    const float* dci = dcinv + n * HW;
    const float* dsi = dsinv + n * HW;
    float up = un[p], vp = vn[p], dcp = dci[p], dsp = dsi[p];
    float acc = 0.f;
    for (int q = tid; q < HW; q += 256) {
        float x = up * vn[q]; x = x < 0.15f ? 0.f : x;
        float y = un[q] * vp; y = y < 0.15f ? 0.f : y;
        float delta = (q == p) ? 1.0f : 0.0f;
        float val = (0.5f * (x + y) + delta) * dcp * dci[q] + (Bb[q] + delta) * dsp * dsi[q];
        acc += val;
    }
    __shared__ float s4[4];
    acc = blockReduceSum(acc, s4);
    if (tid == 0) dfinv[n * HW + p] = 1.0f / sqrtf(acc + 1.0f);
}

// recompute sim_pre, normalize -> split-bf16 sim (SMH/SML) + f32 ACCUM
__global__ void k_norm_accum(const float* __restrict__ B, const float* __restrict__ u,
                             const float* __restrict__ vv, const float* __restrict__ dcinv,
                             const float* __restrict__ dsinv, const float* __restrict__ dfinv,
                             u16* __restrict__ SMH, u16* __restrict__ SML,
                             float* __restrict__ ACC, int first) {
    int p = blockIdx.x, n = blockIdx.y, tid = threadIdx.x;
    const float* Bb = B + (size_t)n * HW * HW + (size_t)p * HW;
    u16* Sh = SMH + (size_t)n * HW * HW + (size_t)p * HW;
    u16* Sl = SML + (size_t)n * HW * HW + (size_t)p * HW;
    float* Ab = ACC + (size_t)n * HW * HW + (size_t)p * HW;
    const float* un = u + n * HW;
    const float* vn = vv + n * HW;
    const float* dci = dcinv + n * HW;
    const float* dsi = dsinv + n * HW;
    const float* df = dfinv + n * HW;
    float up = un[p], vp = vn[p], dcp = dci[p], dsp = dsi[p], dfp = df[p];
    for (int q = tid; q < HW; q += 256) {
        float x = up * vn[q]; x = x < 0.15f ? 0.f : x;
        float y = un[q] * vp; y = y < 0.15f ? 0.f : y;
        float delta = (q == p) ? 1.0f : 0.0f;
        float sim_pre = (0.5f * (x + y) + delta) * dcp * dci[q] + (Bb[q] + delta) * dsp * dsi[q];
        float val = (sim_pre + delta) * dfp * df[q];
        u16 h, l; splitbf(val, h, l);
        Sh[q] = h; Sl[q] = l;
        Ab[q] = first ? val : (Ab[q] + val);
    }
}

__global__ void k_final_rowsum(const float* __restrict__ ACC, float* __restrict__ dinv) {
    int p = blockIdx.x, n = blockIdx.y, tid = threadIdx.x;
    const float* Ab = ACC + (size_t)n * HW * HW + (size_t)p * HW;
    float acc = 0.f;
    for (int q = tid; q < HW; q += 256) acc += Ab[q];
    __shared__ float s4[4];
    acc = blockReduceSum(acc, s4);
    if (tid == 0) dinv[n * HW + p] = 1.0f / sqrtf(acc * (1.0f / 3.0f) + 1.0f);
}

// final normalize -> split-bf16 adjacency (ADJH/ADJL) + per-row stats (no f32 write)
__global__ void k_final_norm(const float* __restrict__ ACC, const float* __restrict__ dinv,
                             u16* __restrict__ ADJH, u16* __restrict__ ADJL,
                             float* __restrict__ rowsf, float* __restrict__ diagrow,
                             float* __restrict__ sqrow) {
    int p = blockIdx.x, n = blockIdx.y, tid = threadIdx.x;
    const float* Ab = ACC + (size_t)n * HW * HW + (size_t)p * HW;
    u16* Oh = ADJH + (size_t)n * HW * HW + (size_t)p * HW;
    u16* Ol = ADJL + (size_t)n * HW * HW + (size_t)p * HW;
    const float* di = dinv + n * HW;
    float dp = di[p];
    float accr = 0.f, accsq = 0.f, accd = 0.f;
    for (int q = tid; q < HW; q += 256) {
        float val = (Ab[q] * (1.0f / 3.0f) + ((q == p) ? 1.f : 0.f)) * dp * di[q];
        u16 h, l; splitbf(val, h, l);
        Oh[q] = h; Ol[q] = l;
        accr += val;
        accsq += val * val;
        if (q == p) accd = val;
    }
    __shared__ float s4[4];
    accr = blockReduceSum(accr, s4);
    accsq = blockReduceSum(accsq, s4);
    accd = blockReduceSum(accd, s4);
    if (tid == 0) {
        rowsf[n * HW + p] = accr;
        sqrow[n * HW + p] = accsq;
        diagrow[n * HW + p] = accd;
    }
}

__global__ void k_scal(const float* __restrict__ diagrow, const float* __restrict__ sqrow,
                       float* __restrict__ scal) {
    int tid = threadIdx.x;
    float a = 0.f, b = 0.f;
    for (int i = tid; i < NB * HW; i += 256) { a += diagrow[i]; b += sqrow[i]; }
    __shared__ float s4[4];
    a = blockReduceSum(a, s4);
    b = blockReduceSum(b, s4);
    if (tid == 0) { scal[0] = a; scal[1] = b; }
}

__global__ void k_reg(const float* __restrict__ rowsf, const float* __restrict__ scal,
                      float* __restrict__ outreg) {
    int n = blockIdx.x, tid = threadIdx.x;
    float acc = 0.f;
    for (int p = tid; p < HW; p += 256) acc += logf(rowsf[n * HW + p]);
    __shared__ float s4[4];
    acc = blockReduceSum(acc, s4);
    if (tid == 0) {
        float f = -0.1f * acc / 1024.0f + 0.1f * sqrtf(scal[1]) / 1048576.0f;
        outreg[n] = 0.1f * scal[0] + f;
    }
}

__global__ void k_appnp_t(const float* __restrict__ ori, const float* __restrict__ wa1,
                          const float* __restrict__ ba1, const float* __restrict__ wa2,
                          const float* __restrict__ ba2, float* __restrict__ T) {
    int p = blockIdx.x, n = blockIdx.y, tid = threadIdx.x;
    const float* x = ori + (size_t)n * C * HW + (size_t)p * C;
    float xv = x[tid];
    __shared__ float s4[4];
    __shared__ float h[3];
    float d0 = blockReduceSum(xv * wa1[0 * C + tid], s4);
    float d1 = blockReduceSum(xv * wa1[1 * C + tid], s4);
    float d2 = blockReduceSum(xv * wa1[2 * C + tid], s4);
    if (tid == 0) {
        h[0] = fmaxf(d0 + ba1[0], 0.f);
        h[1] = fmaxf(d1 + ba1[1], 0.f);
        h[2] = fmaxf(d2 + ba1[2], 0.f);
    }
    __syncthreads();
    float t = h[0] * wa2[tid * 3 + 0] + h[1] * wa2[tid * 3 + 1] + h[2] * wa2[tid * 3 + 2] + ba2[tid];
    T[(size_t)n * HW * C + (size_t)p * C + tid] = fmaxf(t, 0.f);
}

// =====================================================================================
extern "C" void kernel_launch(void* const* d_in, const int* in_sizes, int n_in,
                              void* d_out, int out_size, void* d_ws, size_t ws_size,
                              hipStream_t stream) {
    const float* seg_in = (const float*)d_in[0];
    const float* edge   = (const float*)d_in[1];
    const float* ws1    = (const float*)d_in[2];
    const float* bs1    = (const float*)d_in[3];
    const float* ws11   = (const float*)d_in[4];
    const float* bs11   = (const float*)d_in[5];
    const float* ws2    = (const float*)d_in[6];
    const float* bs2    = (const float*)d_in[7];
    const float* ws3    = (const float*)d_in[8];
    const float* bs3    = (const float*)d_in[9];
    const float* wmlp   = (const float*)d_in[10];
    const float* bmlp   = (const float*)d_in[11];
    const float* wgcn   = (const float*)d_in[12];
    const float* bgcn   = (const float*)d_in[13];
    const float* wa1    = (const float*)d_in[14];
    const float* ba1    = (const float*)d_in[15];
    const float* wa2    = (const float*)d_in[16];
    const float* ba2    = (const float*)d_in[17];

    float* out = (float*)d_out;
    char* wb = (char*)d_ws;
    size_t off = 0;
    auto nf = [&](size_t elems) -> float* {
        float* p = (float*)(wb + off); off += ((elems * 4 + 255) & ~(size_t)255); return p; };
    auto nu = [&](size_t elems) -> u16* {
        u16* p = (u16*)(wb + off); off += ((elems * 2 + 255) & ~(size_t)255); return p; };

    // f32
    float* SEG_A   = nf((size_t)NB * C * HW);     // 8 MB
    float* SEGSC   = nf((size_t)NB * 128 * HW);   // 4 MB
    float* TT      = nf((size_t)NB * C * HW);     // 8 MB  (Tt f32, APPNP residual)
    float* TBUF    = nf((size_t)NB * HW * C);     // 8 MB  (T [pos][ch])
    float* BBUF    = nf((size_t)NB * HW * HW);    // 32 MB (Bsym)
    float* ACCUM   = nf((size_t)NB * HW * HW);    // 32 MB
    float* MAXS    = nf((size_t)8 * NB * HW);
    float* MAXE    = nf((size_t)8 * NB * HW);
    float* BCAT    = nf(128);
    float* ubuf    = nf(NB * HW);
    float* vbuf    = nf(NB * HW);
    float* ssbuf   = nf(NB * HW);
    float* embuf   = nf(NB * HW);
    float* dsum    = nf(NB * HW);
    float* dcinv   = nf(NB * HW);
    float* dsinv   = nf(NB * HW);
    float* dfinv   = nf(NB * HW);
    float* rowsf   = nf(NB * HW);
    float* diagrow = nf(NB * HW);
    float* sqrow   = nf(NB * HW);
    float* pooled  = nf(NB * C);
    float* cabuf   = nf(NB * NS);
    float* scal    = nf(16);
    // u16 hi/lo pairs
    u16* SAH  = nu((size_t)NB * C * HW);   u16* SAL  = nu((size_t)NB * C * HW);    // seg (A of seg@sim)
    u16* TGH  = nu((size_t)NB * HW * C);   u16* TGL  = nu((size_t)NB * HW * C);    // seg^T (B of conv)
    u16* WCH  = nu((size_t)128 * C);       u16* WCL  = nu((size_t)128 * C);        // conv weights
    u16* WGH  = nu((size_t)C * C);         u16* WGL  = nu((size_t)C * C);          // wgcn
    u16* SCH  = nu((size_t)NB * 128 * HW); u16* SCL  = nu((size_t)NB * 128 * HW);  // conv out
    u16* CTH  = nu((size_t)NB * HW * NS);  u16* CTL  = nu((size_t)NB * HW * NS);   // seg_c^T
    u16* SMH  = nu((size_t)NB * HW * HW);  u16* SML  = nu((size_t)NB * HW * HW);   // sim (32 MB)
    u16* SIMTH= nu((size_t)NB * HW * C);   u16* SIMTL= nu((size_t)NB * HW * C);    // seg_sim^T
    u16* TTH  = nu((size_t)NB * C * HW);   u16* TTL  = nu((size_t)NB * C * HW);    // Tt
    u16* X1H  = nu((size_t)NB * C * HW);   u16* X1L  = nu((size_t)NB * C * HW);
    u16* X2H  = nu((size_t)NB * C * HW);   u16* X2L  = nu((size_t)NB * C * HW);
    // overlay: adjacency hi/lo reuses sim buffers (sim dead before final_norm)
    u16* ADJH = SMH;
    u16* ADJL = SML;

    const long long sAdj = (long long)HW * HW;
    const long long sSeg = (long long)C * HW;
    const long long sSC  = (long long)128 * HW;
    const long long sCT  = (long long)HW * NS;

    k_prepw<<<dim3(64), 256, 0, stream>>>(ws1, bs1, ws11, bs11, WCH, WCL, BCAT);
    k_presplit<<<dim3(64), 256, 0, stream>>>(wgcn, WGH, WGL, C * C);
    k_presplit<<<dim3(2048), 256, 0, stream>>>(seg_in, SAH, SAL, NB * C * HW);

    for (int it = 0; it < 3; ++it) {
        const float* seg_src = (it == 0) ? seg_in : SEG_A;
        // seg^T -> split u16 [HW][C]
        k_transp_split<C, HW, false><<<dim3(4, 16, NB), 256, 0, stream>>>(
            seg_src, sSeg, TGH, TGL, nullptr, sSeg);
        // both 1x1 convs: SEGSC f32 + SCH/SCL
        k_mfma3<64, 64, 5><<<dim3(16, 2, NB), 256, 0, stream>>>(
            WCH, WCL, 0, C, TGH, TGL, sSeg, C, C,
            SEGSC, SCH, SCL, sSC, HW, BCAT, nullptr, 0);
        // seg_c^T -> split u16 [HW][64]
        k_transp_split<NS, HW, false><<<dim3(1, 16, NB), 256, 0, stream>>>(
            SEGSC + (size_t)64 * HW, sSC, CTH, CTL, nullptr, sCT);
        k_pooled<<<dim3(C, NB), 256, 0, stream>>>(seg_src, pooled);
        k_ca<<<dim3(NB), 64, 0, stream>>>(pooled, wmlp, bmlp, cabuf);
        k_maxes<<<dim3(4, NB, 8), 256, 0, stream>>>(seg_src, edge, MAXS, MAXE);
        k_maxfin<<<dim3(4, NB), 256, 0, stream>>>(MAXS, MAXE, ws2, bs2, ws3, bs3, ssbuf, embuf);
        k_uv<<<dim3(4, NB, 2), 256, 0, stream>>>(SEGSC, cabuf, ubuf, vbuf);
        hipMemsetAsync(dsum, 0, (size_t)NB * HW * sizeof(float), stream);
        k_bbuild<<<dim3(136, NB), 256, 0, stream>>>(
            SCH + (size_t)64 * HW, SCL + (size_t)64 * HW, sSC,
            CTH, CTL, sCT, embuf, ssbuf, BBUF, dsum);
        k_dinv<<<dim3(HW, NB), 256, 0, stream>>>(ubuf, vbuf, dsum, dcinv, dsinv);
        k_simsum<<<dim3(HW, NB), 256, 0, stream>>>(BBUF, ubuf, vbuf, dcinv, dsinv, dfinv);
        k_norm_accum<<<dim3(HW, NB), 256, 0, stream>>>(BBUF, ubuf, vbuf, dcinv, dsinv, dfinv,
                                                       SMH, SML, ACCUM, it == 0 ? 1 : 0);
        // seg_sim^T = (seg @ sim)^T -> SIMTH/SIMTL [pos][ch]
        k_mfma3<64, 64, 0><<<dim3(16, 4, NB), 256, 0, stream>>>(
            SAH, SAL, sSeg, HW, SMH, SML, sAdj, HW, HW,
            nullptr, SIMTH, SIMTL, sSeg, C, nullptr, nullptr, 0);
        // seg' = relu(wgcn @ seg_sim + bgcn) + seg -> SEG_A f32 + SAH/SAL
        k_mfma3<64, 64, 2><<<dim3(16, 4, NB), 256, 0, stream>>>(
            WGH, WGL, 0, C, SIMTH, SIMTL, sSeg, C, C,
            SEG_A, SAH, SAL, sSeg, HW, bgcn, seg_src, sSeg);
    }

    // final adjacency + regularizer
    k_final_rowsum<<<dim3(HW, NB), 256, 0, stream>>>(ACCUM, dcinv);
    k_final_norm<<<dim3(HW, NB), 256, 0, stream>>>(ACCUM, dcinv, ADJH, ADJL, rowsf, diagrow, sqrow);
    k_scal<<<dim3(1), 256, 0, stream>>>(diagrow, sqrow, scal);
    k_reg<<<dim3(NB), 256, 0, stream>>>(rowsf, scal, out + (size_t)NB * C * HW);

    // APPNP: Yt = 0.5 * Xt @ adj + 0.5 * Tt  (adj symmetric)
    k_appnp_t<<<dim3(HW, NB), 256, 0, stream>>>(seg_in, wa1, ba1, wa2, ba2, TBUF);
    k_transp_split<HW, C, true><<<dim3(16, 4, NB), 256, 0, stream>>>(
        TBUF, sSeg, TTH, TTL, TT, sSeg);
    k_mfma3<64, 64, 3><<<dim3(16, 4, NB), 256, 0, stream>>>(
        TTH, TTL, sSeg, HW, ADJH, ADJL, sAdj, HW, HW,
        nullptr, X1H, X1L, sSeg, HW, nullptr, TT, sSeg);
    k_mfma3<64, 64, 3><<<dim3(16, 4, NB), 256, 0, stream>>>(
        X1H, X1L, sSeg, HW, ADJH, ADJL, sAdj, HW, HW,
        nullptr, X2H, X2L, sSeg, HW, nullptr, TT, sSeg);
    k_mfma3<64, 64, 4><<<dim3(16, 4, NB), 256, 0, stream>>>(
        X2H, X2L, sSeg, HW, ADJH, ADJL, sAdj, HW, HW,
        out, nullptr, nullptr, sSeg, C, nullptr, TT, sSeg);
}